// Round 8
// baseline (4706.955 us; speedup 1.0000x reference)
//
#include <hip/hip_runtime.h>
#include <hip/hip_cooperative_groups.h>
#include <math.h>

namespace cg = cooperative_groups;

#define Tsz 512
#define NBLK 256
#define NTHR 512

// LDS pitches (shorts): dword pitch ≡ 4 (mod 32), 16B-aligned — empirical optimum for
// the MFMA fragment b128 pattern (R5/R8: 2.4e8 conflicts; odd-dw: 4.4e8; ≡0: 1.1e9).
#define PB0 328   // B h0|x rows (320 used)  164 dw
#define PB1 264   // B h1 rows  (256 used)   132 dw
#define B1B 5248  // 16*PB0

// watchdog: ~650x the worst legitimate wait; converts any protocol stall into
// a terminating wrong-answer (diagnosable) instead of a GPU hang.
#define SPIN_GUARD (1 << 17)

typedef short short8  __attribute__((ext_vector_type(8)));
typedef short short4v __attribute__((ext_vector_type(4)));
typedef float float4v __attribute__((ext_vector_type(4)));

#define MFMA16(a, b, c) __builtin_amdgcn_mfma_f32_16x16x32_bf16((a), (b), (c), 0, 0, 0)
#define LOADX(p) __hip_atomic_load((p), __ATOMIC_RELAXED, __HIP_MEMORY_SCOPE_AGENT)
#define STOREX(p, v) __hip_atomic_store((p), (v), __ATOMIC_RELAXED, __HIP_MEMORY_SCOPE_AGENT)

__device__ __forceinline__ float sigm(float x) { return 1.0f / (1.0f + __expf(-x)); }
__device__ __forceinline__ float tanh_fast(float x) { return 2.0f / (1.0f + __expf(-2.0f * x)) - 1.0f; }

// fp32 -> bf16 hi (x) + bf16 lo (y), RNE both
__device__ __forceinline__ short2 split1(float f) {
    unsigned u = __float_as_uint(f);
    unsigned r = u + 0x7FFFu + ((u >> 16) & 1u);
    short h = (short)(r >> 16);
    float hf = __uint_as_float(r & 0xFFFF0000u);
    float d  = f - hf;
    unsigned u2 = __float_as_uint(d);
    unsigned r2 = u2 + 0x7FFFu + ((u2 >> 16) & 1u);
    return make_short2(h, (short)(r2 >> 16));
}

// Weight-stationary 2-layer LSTM, bf16-split-3 MFMA, ONE pass per superstep.
// 256 blocks = 16 row-slices (16 cols) x 16 batch-slices (16 batches).
// M=128 rows (L0 rows 0..63 = gate*16+col, L1 rows 64..127), N=16 batches.
// 8 waves = 8 16x16 tiles, FULL K per wave (L0: K=320 h0|x, L1: K=512 h0|h1).
//
// Sync (R8): PER-WAVE flags. Each wave, after its 64 cell h-stores, drains
// its own vmem (inline s_waitcnt vmcnt(0)) and lane0 stores flag word
// syn[(bs*16+rs)*16 + w]. 8 words live in the block's own 64B line (writers
// are the block's 8 waves — intra-CU). Consumers poll ALL 128 producer-wave
// flags of the bs-group with two 64-lane gathers. This deletes the S3
// barrier entirely: publication happens per-wave as soon as its stores ack,
// not after the block's slowest wave. Anti-lap induction unchanged: flag
// >= s+1 for all 128 waves implies every producer wave completed cell(s),
// hence passed S1(s)/S2(s), hence its staging reads of step s-1 retired.
// Also: 6 MFMA accumulator chains (even/odd kc) for 2x MFMA ILP, and
// x-staging hoisted above the poll (safe: runs after cell(s) > S2(s) which
// ordered all MFMA(s) reads of the x region).
__global__ __launch_bounds__(NTHR, 1)
void lstm2_mfma(const float* __restrict__ x,
                const float* __restrict__ Wih0, const float* __restrict__ Whh0,
                const float* __restrict__ bih0, const float* __restrict__ bhh0,
                const float* __restrict__ Wih1, const float* __restrict__ Whh1,
                const float* __restrict__ bih1, const float* __restrict__ bhh1,
                const float* __restrict__ Wf,   const float* __restrict__ bf,
                float* __restrict__ out, float* __restrict__ ws)
{
    cg::grid_group grid = cg::this_grid();
    const int tid = threadIdx.x;
    const int rs  = blockIdx.x >> 4;   // row-slice: cols [rs*16, rs*16+16)
    const int bs  = blockIdx.x & 15;   // batch-slice: batches [bs*16, bs*16+16)
    const int bbase = bs * 16;

    __shared__ short Bh[2][9472];      // 37.9 KB (h0|x: 16*PB0, h1: 16*PB1)
    __shared__ float zf[128][17];      // 8.7 KB

    unsigned* h0u = (unsigned*)ws;             // [2 parity][256 batch][256 col] packed
    unsigned* h1u = (unsigned*)ws + 2 * 256 * 256;
    unsigned* syn = (unsigned*)ws + 4 * 256 * 256;
    // per-wave flags: syn[(bs*16+rs)*16 + w], 8 words in the block's 64B line

    // ---- init ----
    for (int i = blockIdx.x * NTHR + tid; i < 4 * 256 * 256; i += NBLK * NTHR)
        ((unsigned*)ws)[i] = 0u;
    if (tid < 8) STOREX(&syn[(bs * 16 + rs) * 16 + tid], 0u);
    if (rs == 0 && tid < 16) out[bbase + tid] = bf[0];

    // ---- mfma lane decode ----
    const int w = tid >> 6, lane = tid & 63;
    const int quad = lane >> 4, n16 = lane & 15;
    const int bBase0 = n16 * PB0 + quad * 8;
    const int bBase1 = B1B + n16 * PB1 + quad * 8;

    // ---- weight A-fragments -> registers (full K per wave) ----
    // Wave w<4: L0 tile rows w*16..+16 (within-layer row r = w*16+n16).
    // Wave w>=4: L1 tile rows (w-4)*16..+16.
    short8 wfh[16], wfl[16];
    {
        const int r = (w & 3) * 16 + n16;            // within-layer row 0..63
        const int g = r >> 4, cc = r & 15;
        const size_t grow = (size_t)(g * 256 + rs * 16 + cc);
        const int nkc = (w < 4) ? 10 : 16;
        #pragma unroll
        for (int kc = 0; kc < 16; ++kc) {
            if (kc < nkc) {
                const int k = kc * 32 + quad * 8;
                const float* src;
                if (w < 4)                           // L0: k<256 -> Whh0, else Wih0
                    src = (k < 256) ? &Whh0[grow * 256 + k] : &Wih0[grow * 64 + (k - 256)];
                else                                 // L1: k<256 -> Wih1 (vs h0), else Whh1 (vs h1)
                    src = (k < 256) ? &Wih1[grow * 256 + k] : &Whh1[grow * 256 + (k - 256)];
                float4 f0 = *(const float4*)src;
                float4 f1 = *(const float4*)(src + 4);
                short8 hi, lo; short2 t;
                t = split1(f0.x); hi[0] = t.x; lo[0] = t.y;
                t = split1(f0.y); hi[1] = t.x; lo[1] = t.y;
                t = split1(f0.z); hi[2] = t.x; lo[2] = t.y;
                t = split1(f0.w); hi[3] = t.x; lo[3] = t.y;
                t = split1(f1.x); hi[4] = t.x; lo[4] = t.y;
                t = split1(f1.y); hi[5] = t.x; lo[5] = t.y;
                t = split1(f1.z); hi[6] = t.x; lo[6] = t.y;
                t = split1(f1.w); hi[7] = t.x; lo[7] = t.y;
                wfh[kc] = hi; wfl[kc] = lo;
            }
        }
    }

    // ---- updater decode: all 512 threads, cell (layer ul, col ucc, batch ub) ----
    const int ul = tid >> 8, ub = (tid >> 4) & 15, ucc = tid & 15;
    const int ucol = rs * 16 + ucc;
    float ubias[4];
    {
        const float* bi = ul ? bih1 : bih0;
        const float* bh = ul ? bhh1 : bhh0;
        #pragma unroll
        for (int g = 0; g < 4; ++g) ubias[g] = bi[g * 256 + ucol] + bh[g * 256 + ucol];
    }
    float cst = 0.f, h1last = 0.f;

    // staging decode
    const int sn = tid >> 5, sk = (tid & 31) * 8;
    const int xn = tid >> 4, xd4 = (tid & 15) * 4;

    grid.sync();   // init visible device-wide

    float4 xpre;
    if (tid < 256)
        xpre = *(const float4*)&x[((size_t)(bbase + xn) * Tsz + 0) * 64 + xd4];

    for (int s = 0; s <= Tsz; ++s) {
        const int rp = (s + 1) & 1;   // parity of h0[s-1]
        const int rq = s & 1;         // parity of h1[s-2]

        // ---- x staging hoisted PRE-POLL (local only; S2(s-1) already ordered
        //      all MFMA(s-1) reads of this Bh region) ----
        if (s < Tsz && tid < 256) {
            float4 xv = xpre;
            short4v xh, xl; short2 t;
            t = split1(xv.x); xh[0] = t.x; xl[0] = t.y;
            t = split1(xv.y); xh[1] = t.x; xl[1] = t.y;
            t = split1(xv.z); xh[2] = t.x; xl[2] = t.y;
            t = split1(xv.w); xh[3] = t.x; xl[3] = t.y;
            *(short4v*)&Bh[0][xn * PB0 + 256 + xd4] = xh;
            *(short4v*)&Bh[1][xn * PB0 + 256 + xd4] = xl;
        }

        // ---- wait for superstep s-1: all 128 producer-wave flags >= s,
        //      two 64-lane gathers across the 16 per-block lines ----
        if (s > 0) {
            const unsigned* f1 = &syn[(bs * 16 + (lane >> 2)) * 16 + (lane & 3)];
            const unsigned* f2 = f1 + 4;   // waves 4..7
            int guard = 0;
            for (;;) {
                unsigned v1 = LOADX(f1);
                unsigned v2 = LOADX(f2);
                bool ok = (v1 >= (unsigned)s) & (v2 >= (unsigned)s);
                if (__all((int)ok)) break;
                if (++guard > SPIN_GUARD) break;   // watchdog: fail, don't hang
            }
        }

        // ---- stage h0[s-1], h1[s-2] (packed-uint load + v_perm unpack) ----
        {
            const unsigned* q0 = &h0u[((size_t)(rp * 256) + bbase + sn) * 256 + sk];
            const unsigned* q1 = &h1u[((size_t)(rq * 256) + bbase + sn) * 256 + sk];
            unsigned a[8], b[8];
            #pragma unroll
            for (int i = 0; i < 8; ++i) a[i] = LOADX(q0 + i);
            #pragma unroll
            for (int i = 0; i < 8; ++i) b[i] = LOADX(q1 + i);
            uint4 hi4, lo4;
            hi4.x = __builtin_amdgcn_perm(a[1], a[0], 0x07060302u);
            hi4.y = __builtin_amdgcn_perm(a[3], a[2], 0x07060302u);
            hi4.z = __builtin_amdgcn_perm(a[5], a[4], 0x07060302u);
            hi4.w = __builtin_amdgcn_perm(a[7], a[6], 0x07060302u);
            lo4.x = __builtin_amdgcn_perm(a[1], a[0], 0x05040100u);
            lo4.y = __builtin_amdgcn_perm(a[3], a[2], 0x05040100u);
            lo4.z = __builtin_amdgcn_perm(a[5], a[4], 0x05040100u);
            lo4.w = __builtin_amdgcn_perm(a[7], a[6], 0x05040100u);
            *(uint4*)&Bh[0][sn * PB0 + sk] = hi4;
            *(uint4*)&Bh[1][sn * PB0 + sk] = lo4;
            hi4.x = __builtin_amdgcn_perm(b[1], b[0], 0x07060302u);
            hi4.y = __builtin_amdgcn_perm(b[3], b[2], 0x07060302u);
            hi4.z = __builtin_amdgcn_perm(b[5], b[4], 0x07060302u);
            hi4.w = __builtin_amdgcn_perm(b[7], b[6], 0x07060302u);
            lo4.x = __builtin_amdgcn_perm(b[1], b[0], 0x05040100u);
            lo4.y = __builtin_amdgcn_perm(b[3], b[2], 0x05040100u);
            lo4.z = __builtin_amdgcn_perm(b[5], b[4], 0x05040100u);
            lo4.w = __builtin_amdgcn_perm(b[7], b[6], 0x05040100u);
            *(uint4*)&Bh[0][B1B + sn * PB1 + sk] = hi4;
            *(uint4*)&Bh[1][B1B + sn * PB1 + sk] = lo4;
        }
        __syncthreads();   // S1: Bh staged

        // x prefetch for next superstep (drains naturally before use)
        if (tid < 256 && s + 1 < Tsz)
            xpre = *(const float4*)&x[((size_t)(bbase + xn) * Tsz + (s + 1)) * 64 + xd4];

        // ---- MFMA: full-K tile per wave, register A-frags, SIX independent
        //      accumulator chains (even/odd kc x {hh, hl, lh}) for 2x ILP ----
        float4v a0 = {0.f, 0.f, 0.f, 0.f};
        float4v a1 = {0.f, 0.f, 0.f, 0.f};
        float4v a2 = {0.f, 0.f, 0.f, 0.f};
        float4v a3 = {0.f, 0.f, 0.f, 0.f};
        float4v a4 = {0.f, 0.f, 0.f, 0.f};
        float4v a5 = {0.f, 0.f, 0.f, 0.f};
        if (w < 4) {                         // L0: K=320 over h0|x
            #pragma unroll
            for (int kc = 0; kc < 10; kc += 2) {
                const int boa = bBase0 + kc * 32;
                const int bob = bBase0 + (kc + 1) * 32;
                short8 bha = *(const short8*)&Bh[0][boa];
                short8 bla = *(const short8*)&Bh[1][boa];
                short8 bhb = *(const short8*)&Bh[0][bob];
                short8 blb = *(const short8*)&Bh[1][bob];
                a0 = MFMA16(wfh[kc],     bha, a0);
                a3 = MFMA16(wfh[kc + 1], bhb, a3);
                a1 = MFMA16(wfh[kc],     bla, a1);
                a4 = MFMA16(wfh[kc + 1], blb, a4);
                a2 = MFMA16(wfl[kc],     bha, a2);
                a5 = MFMA16(wfl[kc + 1], bhb, a5);
            }
        } else {                             // L1: K=512 (h0 then h1)
            #pragma unroll
            for (int kc = 0; kc < 8; kc += 2) {
                const int boa = bBase0 + kc * 32;
                const int bob = bBase0 + (kc + 1) * 32;
                short8 bha = *(const short8*)&Bh[0][boa];
                short8 bla = *(const short8*)&Bh[1][boa];
                short8 bhb = *(const short8*)&Bh[0][bob];
                short8 blb = *(const short8*)&Bh[1][bob];
                a0 = MFMA16(wfh[kc],     bha, a0);
                a3 = MFMA16(wfh[kc + 1], bhb, a3);
                a1 = MFMA16(wfh[kc],     bla, a1);
                a4 = MFMA16(wfh[kc + 1], blb, a4);
                a2 = MFMA16(wfl[kc],     bha, a2);
                a5 = MFMA16(wfl[kc + 1], bhb, a5);
            }
            #pragma unroll
            for (int kc = 8; kc < 16; kc += 2) {
                const int boa = bBase1 + (kc - 8) * 32;
                const int bob = bBase1 + (kc - 7) * 32;
                short8 bha = *(const short8*)&Bh[0][boa];
                short8 bla = *(const short8*)&Bh[1][boa];
                short8 bhb = *(const short8*)&Bh[0][bob];
                short8 blb = *(const short8*)&Bh[1][bob];
                a0 = MFMA16(wfh[kc],     bha, a0);
                a3 = MFMA16(wfh[kc + 1], bhb, a3);
                a1 = MFMA16(wfh[kc],     bla, a1);
                a4 = MFMA16(wfh[kc + 1], blb, a4);
                a2 = MFMA16(wfl[kc],     bha, a2);
                a5 = MFMA16(wfl[kc + 1], bhb, a5);
            }
        }
        float4v acc = ((a0 + a3) + (a1 + a4)) + (a2 + a5);
        #pragma unroll
        for (int r = 0; r < 4; ++r)
            zf[w * 16 + quad * 4 + r][n16] = acc[r];
        __syncthreads();   // S2: zf complete; ALL MFMA Bh reads done

        // ---- cell update (all 512 threads own one cell) ----
        {
            const bool active = ul ? (s >= 1) : (s < Tsz);
            if (active) {
                const int mb = ul * 64 + ucc;
                float z0 = zf[mb +  0][ub] + ubias[0];
                float z1 = zf[mb + 16][ub] + ubias[1];
                float z2 = zf[mb + 32][ub] + ubias[2];
                float z3 = zf[mb + 48][ub] + ubias[3];
                float ii = sigm(z0), ff = sigm(z1);
                float gg = tanh_fast(z2), oo = sigm(z3);
                float c = ff * cst + ii * gg; cst = c;
                float hval = oo * tanh_fast(c);
                short2 hl = split1(hval);
                unsigned pk = ((unsigned)(unsigned short)hl.x << 16) |
                              (unsigned)(unsigned short)hl.y;
                if (ul) {
                    h1last = hval;
                    STOREX(&h1u[((size_t)(((s + 1) & 1) * 256) + bbase + ub) * 256 + ucol], pk);
                } else {
                    STOREX(&h0u[((size_t)((s & 1) * 256) + bbase + ub) * 256 + ucol], pk);
                }
            }
        }

        // ---- per-wave publish: drain own vmem (h stores acked at coherence
        //      point), then lane0 stores this wave's flag. NO S3 barrier. ----
        asm volatile("s_waitcnt vmcnt(0)" ::: "memory");
        if (lane == 0)
            STOREX(&syn[(bs * 16 + rs) * 16 + w], (unsigned)(s + 1));
    }

    // ---- epilogue: out[b] += sum_cols h1_final * Wf ----
    if (ul == 1) {
        atomicAdd(&out[bbase + ub], h1last * Wf[ucol]);
    }
}

extern "C" void kernel_launch(void* const* d_in, const int* in_sizes, int n_in,
                              void* d_out, int out_size, void* d_ws, size_t ws_size,
                              hipStream_t stream) {
    const float* x    = (const float*)d_in[0];
    const float* Wih0 = (const float*)d_in[1];
    const float* Whh0 = (const float*)d_in[2];
    const float* bih0 = (const float*)d_in[3];
    const float* bhh0 = (const float*)d_in[4];
    const float* Wih1 = (const float*)d_in[5];
    const float* Whh1 = (const float*)d_in[6];
    const float* bih1 = (const float*)d_in[7];
    const float* bhh1 = (const float*)d_in[8];
    const float* Wf   = (const float*)d_in[9];
    const float* bf   = (const float*)d_in[10];
    float* out = (float*)d_out;
    float* ws  = (float*)d_ws;   // 1 MB packed h buffers + 16 KB flag area

    void* args[] = {
        (void*)&x, (void*)&Wih0, (void*)&Whh0, (void*)&bih0, (void*)&bhh0,
        (void*)&Wih1, (void*)&Whh1, (void*)&bih1, (void*)&bhh1,
        (void*)&Wf, (void*)&bf, (void*)&out, (void*)&ws
    };
    hipLaunchCooperativeKernel((void*)lstm2_mfma, dim3(NBLK), dim3(NTHR),
                               args, 0, stream);
}

// Round 9
// 1826.521 us; speedup vs baseline: 2.5770x; 2.5770x over previous
//
#include <hip/hip_runtime.h>
#include <hip/hip_cooperative_groups.h>
#include <math.h>

namespace cg = cooperative_groups;

#define Tsz 512
#define NBLK 256
#define NTHR 512

// LDS pitches (shorts): dword pitch ≡ 4 (mod 32), 16B-aligned — empirical optimum for
// the MFMA fragment b128 pattern (R5/R8: 2.4e8 conflicts; odd-dw: 4.4e8; ≡0: 1.1e9).
#define PB0 328   // B h0|x rows (320 used)  164 dw
#define PB1 264   // B h1 rows  (256 used)   132 dw
#define B1B 5248  // 16*PB0

// watchdog: ~650x the worst legitimate wait; converts any protocol stall into
// a terminating wrong-answer (diagnosable) instead of a GPU hang.
#define SPIN_GUARD (1 << 17)

typedef short short8  __attribute__((ext_vector_type(8)));
typedef short short4v __attribute__((ext_vector_type(4)));
typedef float float4v __attribute__((ext_vector_type(4)));
typedef unsigned int uint4v __attribute__((ext_vector_type(4)));

#define MFMA16(a, b, c) __builtin_amdgcn_mfma_f32_16x16x32_bf16((a), (b), (c), 0, 0, 0)
#define LOADX(p) __hip_atomic_load((p), __ATOMIC_RELAXED, __HIP_MEMORY_SCOPE_AGENT)
#define STOREX(p, v) __hip_atomic_store((p), (v), __ATOMIC_RELAXED, __HIP_MEMORY_SCOPE_AGENT)

__device__ __forceinline__ float sigm(float x) { return 1.0f / (1.0f + __expf(-x)); }
__device__ __forceinline__ float tanh_fast(float x) { return 2.0f / (1.0f + __expf(-2.0f * x)) - 1.0f; }

// fp32 -> bf16 hi (x) + bf16 lo (y), RNE both
__device__ __forceinline__ short2 split1(float f) {
    unsigned u = __float_as_uint(f);
    unsigned r = u + 0x7FFFu + ((u >> 16) & 1u);
    short h = (short)(r >> 16);
    float hf = __uint_as_float(r & 0xFFFF0000u);
    float d  = f - hf;
    unsigned u2 = __float_as_uint(d);
    unsigned r2 = u2 + 0x7FFFu + ((u2 >> 16) & 1u);
    return make_short2(h, (short)(r2 >> 16));
}

// 16B coherent (L1-bypass) load: equivalent ordering/visibility to four
// agent-scope relaxed dword loads, but ONE L2 request instead of four.
// sc0 is mandatory: plain dwordx4 could hit stale per-CU L1 lines from the
// read of the same parity buffer two supersteps ago.
__device__ __forceinline__ uint4v load16_sc0(const unsigned* p) {
    uint4v r;
    asm volatile("global_load_dwordx4 %0, %1, off sc0"
                 : "=v"(r) : "v"(p) : "memory");
    return r;
}

// Weight-stationary 2-layer LSTM, bf16-split-3 MFMA, ONE pass per superstep.
// 256 blocks = 16 row-slices (16 cols) x 16 batch-slices (16 batches).
// M=128 rows (L0 rows 0..63 = gate*16+col, L1 rows 64..127), N=16 batches.
// 8 waves = 8 16x16 tiles, FULL K per wave (L0: K=320 h0|x, L1: K=512 h0|h1).
//
// Sync (R9 = R7 skeleton): data stores -> S3 drain -> one relaxed flag store
// per block to its OWN 64B line; consumers 16-lane gather-poll + s_sleep.
// R9 change: staging loads widened 4B -> 16B (global_load_dwordx4 sc0).
// All 16 blocks of a bs-group read the SAME h lines each step; scalar loads
// made ~256 requests/line/group-step queueing at the L2 bank. 16B loads cut
// that 4x — attacking the dominant unexplained wait term.
__global__ __launch_bounds__(NTHR, 1)
void lstm2_mfma(const float* __restrict__ x,
                const float* __restrict__ Wih0, const float* __restrict__ Whh0,
                const float* __restrict__ bih0, const float* __restrict__ bhh0,
                const float* __restrict__ Wih1, const float* __restrict__ Whh1,
                const float* __restrict__ bih1, const float* __restrict__ bhh1,
                const float* __restrict__ Wf,   const float* __restrict__ bf,
                float* __restrict__ out, float* __restrict__ ws)
{
    cg::grid_group grid = cg::this_grid();
    const int tid = threadIdx.x;
    const int rs  = blockIdx.x >> 4;   // row-slice: cols [rs*16, rs*16+16)
    const int bs  = blockIdx.x & 15;   // batch-slice: batches [bs*16, bs*16+16)
    const int bbase = bs * 16;

    __shared__ short Bh[2][9472];      // 37.9 KB (h0|x: 16*PB0, h1: 16*PB1)
    __shared__ float zf[128][17];      // 8.7 KB

    unsigned* h0u = (unsigned*)ws;             // [2 parity][256 batch][256 col] packed
    unsigned* h1u = (unsigned*)ws + 2 * 256 * 256;
    unsigned* syn = (unsigned*)ws + 4 * 256 * 256;
    // flag(bs,rs) = syn[(bs*16+rs)*16] -> 256 flags, one 64B line each, 16KB

    // ---- init ----
    for (int i = blockIdx.x * NTHR + tid; i < 4 * 256 * 256; i += NBLK * NTHR)
        ((unsigned*)ws)[i] = 0u;
    if (tid == 0) STOREX(&syn[(bs * 16 + rs) * 16], 0u);
    if (rs == 0 && tid < 16) out[bbase + tid] = bf[0];

    // ---- mfma lane decode ----
    const int w = tid >> 6, lane = tid & 63;
    const int quad = lane >> 4, n16 = lane & 15;
    const int bBase0 = n16 * PB0 + quad * 8;
    const int bBase1 = B1B + n16 * PB1 + quad * 8;

    // ---- weight A-fragments -> registers (full K per wave) ----
    // Wave w<4: L0 tile rows w*16..+16 (within-layer row r = w*16+n16).
    // Wave w>=4: L1 tile rows (w-4)*16..+16.
    short8 wfh[16], wfl[16];
    {
        const int r = (w & 3) * 16 + n16;            // within-layer row 0..63
        const int g = r >> 4, cc = r & 15;
        const size_t grow = (size_t)(g * 256 + rs * 16 + cc);
        const int nkc = (w < 4) ? 10 : 16;
        #pragma unroll
        for (int kc = 0; kc < 16; ++kc) {
            if (kc < nkc) {
                const int k = kc * 32 + quad * 8;
                const float* src;
                if (w < 4)                           // L0: k<256 -> Whh0, else Wih0
                    src = (k < 256) ? &Whh0[grow * 256 + k] : &Wih0[grow * 64 + (k - 256)];
                else                                 // L1: k<256 -> Wih1 (vs h0), else Whh1 (vs h1)
                    src = (k < 256) ? &Wih1[grow * 256 + k] : &Whh1[grow * 256 + (k - 256)];
                float4 f0 = *(const float4*)src;
                float4 f1 = *(const float4*)(src + 4);
                short8 hi, lo; short2 t;
                t = split1(f0.x); hi[0] = t.x; lo[0] = t.y;
                t = split1(f0.y); hi[1] = t.x; lo[1] = t.y;
                t = split1(f0.z); hi[2] = t.x; lo[2] = t.y;
                t = split1(f0.w); hi[3] = t.x; lo[3] = t.y;
                t = split1(f1.x); hi[4] = t.x; lo[4] = t.y;
                t = split1(f1.y); hi[5] = t.x; lo[5] = t.y;
                t = split1(f1.z); hi[6] = t.x; lo[6] = t.y;
                t = split1(f1.w); hi[7] = t.x; lo[7] = t.y;
                wfh[kc] = hi; wfl[kc] = lo;
            }
        }
    }

    // ---- updater decode: all 512 threads, cell (layer ul, col ucc, batch ub) ----
    const int ul = tid >> 8, ub = (tid >> 4) & 15, ucc = tid & 15;
    const int ucol = rs * 16 + ucc;
    float ubias[4];
    {
        const float* bi = ul ? bih1 : bih0;
        const float* bh = ul ? bhh1 : bhh0;
        #pragma unroll
        for (int g = 0; g < 4; ++g) ubias[g] = bi[g * 256 + ucol] + bh[g * 256 + ucol];
    }
    float cst = 0.f, h1last = 0.f;

    // staging decode
    const int sn = tid >> 5, sk = (tid & 31) * 8;
    const int xn = tid >> 4, xd4 = (tid & 15) * 4;

    grid.sync();   // init visible device-wide

    float4 xpre;
    if (tid < 256)
        xpre = *(const float4*)&x[((size_t)(bbase + xn) * Tsz + 0) * 64 + xd4];

    for (int s = 0; s <= Tsz; ++s) {
        const int rp = (s + 1) & 1;   // parity of h0[s-1]
        const int rq = s & 1;         // parity of h1[s-2]

        // ---- wait for superstep s-1 of this bs-group: 16-lane gather poll
        //      across 16 DISTINCT cachelines (read-shared, no line stealing) ----
        if (s > 0) {
            const unsigned* fl = &syn[(bs * 16 + (lane & 15)) * 16];
            int guard = 0;
            while (!__all((int)(LOADX(fl) >= (unsigned)s))) {
                if (++guard > SPIN_GUARD) break;   // watchdog: fail, don't hang
                __builtin_amdgcn_s_sleep(1);
            }
            asm volatile("" ::: "memory");   // keep staging loads below the poll
        }

        // ---- stage h0[s-1], h1[s-2]: 16B sc0 loads (4 L2 requests/thread
        //      instead of 16) + v_perm unpack, x[s] ----
        {
            const unsigned* q0 = &h0u[((size_t)(rp * 256) + bbase + sn) * 256 + sk];
            const unsigned* q1 = &h1u[((size_t)(rq * 256) + bbase + sn) * 256 + sk];
            uint4v A0 = load16_sc0(q0);
            uint4v A1 = load16_sc0(q0 + 4);
            uint4v B0 = load16_sc0(q1);
            uint4v B1 = load16_sc0(q1 + 4);
            asm volatile("s_waitcnt vmcnt(0)" ::: "memory");
            unsigned a[8], b[8];
            a[0] = A0.x; a[1] = A0.y; a[2] = A0.z; a[3] = A0.w;
            a[4] = A1.x; a[5] = A1.y; a[6] = A1.z; a[7] = A1.w;
            b[0] = B0.x; b[1] = B0.y; b[2] = B0.z; b[3] = B0.w;
            b[4] = B1.x; b[5] = B1.y; b[6] = B1.z; b[7] = B1.w;
            uint4 hi4, lo4;
            hi4.x = __builtin_amdgcn_perm(a[1], a[0], 0x07060302u);
            hi4.y = __builtin_amdgcn_perm(a[3], a[2], 0x07060302u);
            hi4.z = __builtin_amdgcn_perm(a[5], a[4], 0x07060302u);
            hi4.w = __builtin_amdgcn_perm(a[7], a[6], 0x07060302u);
            lo4.x = __builtin_amdgcn_perm(a[1], a[0], 0x05040100u);
            lo4.y = __builtin_amdgcn_perm(a[3], a[2], 0x05040100u);
            lo4.z = __builtin_amdgcn_perm(a[5], a[4], 0x05040100u);
            lo4.w = __builtin_amdgcn_perm(a[7], a[6], 0x05040100u);
            *(uint4*)&Bh[0][sn * PB0 + sk] = hi4;
            *(uint4*)&Bh[1][sn * PB0 + sk] = lo4;
            hi4.x = __builtin_amdgcn_perm(b[1], b[0], 0x07060302u);
            hi4.y = __builtin_amdgcn_perm(b[3], b[2], 0x07060302u);
            hi4.z = __builtin_amdgcn_perm(b[5], b[4], 0x07060302u);
            hi4.w = __builtin_amdgcn_perm(b[7], b[6], 0x07060302u);
            lo4.x = __builtin_amdgcn_perm(b[1], b[0], 0x05040100u);
            lo4.y = __builtin_amdgcn_perm(b[3], b[2], 0x05040100u);
            lo4.z = __builtin_amdgcn_perm(b[5], b[4], 0x05040100u);
            lo4.w = __builtin_amdgcn_perm(b[7], b[6], 0x05040100u);
            *(uint4*)&Bh[0][B1B + sn * PB1 + sk] = hi4;
            *(uint4*)&Bh[1][B1B + sn * PB1 + sk] = lo4;
        }
        if (s < Tsz && tid < 256) {
            float4 xv = xpre;
            short4v xh, xl; short2 t;
            t = split1(xv.x); xh[0] = t.x; xl[0] = t.y;
            t = split1(xv.y); xh[1] = t.x; xl[1] = t.y;
            t = split1(xv.z); xh[2] = t.x; xl[2] = t.y;
            t = split1(xv.w); xh[3] = t.x; xl[3] = t.y;
            *(short4v*)&Bh[0][xn * PB0 + 256 + xd4] = xh;
            *(short4v*)&Bh[1][xn * PB0 + 256 + xd4] = xl;
        }
        __syncthreads();   // S1: Bh staged

        // x prefetch for next superstep (drains naturally before use)
        if (tid < 256 && s + 1 < Tsz)
            xpre = *(const float4*)&x[((size_t)(bbase + xn) * Tsz + (s + 1)) * 64 + xd4];

        // ---- MFMA: full-K tile per wave, register A-frags, 3 independent
        //      accumulator chains (hi*hi / hi*lo / lo*hi) ----
        float4v a0 = {0.f, 0.f, 0.f, 0.f};
        float4v a1 = {0.f, 0.f, 0.f, 0.f};
        float4v a2 = {0.f, 0.f, 0.f, 0.f};
        if (w < 4) {                         // L0: K=320 over h0|x
            #pragma unroll
            for (int kc = 0; kc < 10; ++kc) {
                const int bo = bBase0 + kc * 32;
                short8 bh2 = *(const short8*)&Bh[0][bo];
                short8 bl2 = *(const short8*)&Bh[1][bo];
                a0 = MFMA16(wfh[kc], bh2, a0);
                a1 = MFMA16(wfh[kc], bl2, a1);
                a2 = MFMA16(wfl[kc], bh2, a2);
            }
        } else {                             // L1: K=512 (h0 then h1)
            #pragma unroll
            for (int kc = 0; kc < 8; ++kc) {
                const int bo = bBase0 + kc * 32;
                short8 bh2 = *(const short8*)&Bh[0][bo];
                short8 bl2 = *(const short8*)&Bh[1][bo];
                a0 = MFMA16(wfh[kc], bh2, a0);
                a1 = MFMA16(wfh[kc], bl2, a1);
                a2 = MFMA16(wfl[kc], bh2, a2);
            }
            #pragma unroll
            for (int kc = 8; kc < 16; ++kc) {
                const int bo = bBase1 + (kc - 8) * 32;
                short8 bh2 = *(const short8*)&Bh[0][bo];
                short8 bl2 = *(const short8*)&Bh[1][bo];
                a0 = MFMA16(wfh[kc], bh2, a0);
                a1 = MFMA16(wfh[kc], bl2, a1);
                a2 = MFMA16(wfl[kc], bh2, a2);
            }
        }
        float4v acc = (a0 + a1) + a2;
        #pragma unroll
        for (int r = 0; r < 4; ++r)
            zf[w * 16 + quad * 4 + r][n16] = acc[r];
        __syncthreads();   // S2: zf complete

        // ---- cell update (all 512 threads own one cell) ----
        {
            const bool active = ul ? (s >= 1) : (s < Tsz);
            if (active) {
                const int mb = ul * 64 + ucc;
                float z0 = zf[mb +  0][ub] + ubias[0];
                float z1 = zf[mb + 16][ub] + ubias[1];
                float z2 = zf[mb + 32][ub] + ubias[2];
                float z3 = zf[mb + 48][ub] + ubias[3];
                float ii = sigm(z0), ff = sigm(z1);
                float gg = tanh_fast(z2), oo = sigm(z3);
                float c = ff * cst + ii * gg; cst = c;
                float hval = oo * tanh_fast(c);
                short2 hl = split1(hval);
                unsigned pk = ((unsigned)(unsigned short)hl.x << 16) |
                              (unsigned)(unsigned short)hl.y;
                if (ul) {
                    h1last = hval;
                    STOREX(&h1u[((size_t)(((s + 1) & 1) * 256) + bbase + ub) * 256 + ucol], pk);
                } else {
                    STOREX(&h0u[((size_t)((s & 1) * 256) + bbase + ub) * 256 + ucol], pk);
                }
            }
        }

        // ---- drain (S3: per-wave vmcnt(0) before barrier -> h stores done),
        //      then one parallel store to our OWN flag line ----
        __syncthreads();   // S3
        if (tid == 0)
            STOREX(&syn[(bs * 16 + rs) * 16], (unsigned)(s + 1));
    }

    // ---- epilogue: out[b] += sum_cols h1_final * Wf ----
    if (ul == 1) {
        atomicAdd(&out[bbase + ub], h1last * Wf[ucol]);
    }
}

extern "C" void kernel_launch(void* const* d_in, const int* in_sizes, int n_in,
                              void* d_out, int out_size, void* d_ws, size_t ws_size,
                              hipStream_t stream) {
    const float* x    = (const float*)d_in[0];
    const float* Wih0 = (const float*)d_in[1];
    const float* Whh0 = (const float*)d_in[2];
    const float* bih0 = (const float*)d_in[3];
    const float* bhh0 = (const float*)d_in[4];
    const float* Wih1 = (const float*)d_in[5];
    const float* Whh1 = (const float*)d_in[6];
    const float* bih1 = (const float*)d_in[7];
    const float* bhh1 = (const float*)d_in[8];
    const float* Wf   = (const float*)d_in[9];
    const float* bf   = (const float*)d_in[10];
    float* out = (float*)d_out;
    float* ws  = (float*)d_ws;   // 1 MB packed h buffers + 16 KB flag area

    void* args[] = {
        (void*)&x, (void*)&Wih0, (void*)&Whh0, (void*)&bih0, (void*)&bhh0,
        (void*)&Wih1, (void*)&Whh1, (void*)&bih1, (void*)&bhh1,
        (void*)&Wf, (void*)&bf, (void*)&out, (void*)&ws
    };
    hipLaunchCooperativeKernel((void*)lstm2_mfma, dim3(NBLK), dim3(NTHR),
                               args, 0, stream);
}

// Round 10
// 1732.511 us; speedup vs baseline: 2.7168x; 1.0543x over previous
//
#include <hip/hip_runtime.h>
#include <hip/hip_cooperative_groups.h>
#include <math.h>

namespace cg = cooperative_groups;

#define Tsz 512
#define NBLK 256
#define NTHR 512

// LDS pitches (shorts): dword pitch ≡ 4 (mod 32), 16B-aligned — empirical optimum for
// the MFMA fragment b128 pattern (R5/R8: 2.4e8 conflicts; odd-dw: 4.4e8; ≡0: 1.1e9).
#define PB0 328   // B h0|x rows (320 used)  164 dw
#define PB1 264   // B h1 rows  (256 used)   132 dw
#define B1B 5248  // 16*PB0

// watchdog: ~650x the worst legitimate wait; converts any protocol stall into
// a terminating wrong-answer (diagnosable) instead of a GPU hang.
#define SPIN_GUARD (1 << 17)

typedef short short8  __attribute__((ext_vector_type(8)));
typedef short short4v __attribute__((ext_vector_type(4)));
typedef float float4v __attribute__((ext_vector_type(4)));
typedef unsigned int uint4v __attribute__((ext_vector_type(4)));

#define MFMA16(a, b, c) __builtin_amdgcn_mfma_f32_16x16x32_bf16((a), (b), (c), 0, 0, 0)
#define LOADX(p) __hip_atomic_load((p), __ATOMIC_RELAXED, __HIP_MEMORY_SCOPE_AGENT)
#define STOREX(p, v) __hip_atomic_store((p), (v), __ATOMIC_RELAXED, __HIP_MEMORY_SCOPE_AGENT)

__device__ __forceinline__ float sigm(float x) { return 1.0f / (1.0f + __expf(-x)); }
__device__ __forceinline__ float tanh_fast(float x) { return 2.0f / (1.0f + __expf(-2.0f * x)) - 1.0f; }

// fp32 -> bf16 hi (x) + bf16 lo (y), RNE both
__device__ __forceinline__ short2 split1(float f) {
    unsigned u = __float_as_uint(f);
    unsigned r = u + 0x7FFFu + ((u >> 16) & 1u);
    short h = (short)(r >> 16);
    float hf = __uint_as_float(r & 0xFFFF0000u);
    float d  = f - hf;
    unsigned u2 = __float_as_uint(d);
    unsigned r2 = u2 + 0x7FFFu + ((u2 >> 16) & 1u);
    return make_short2(h, (short)(r2 >> 16));
}

// 16B coherent (L1-bypass) load: equivalent visibility to four agent-scope
// relaxed dword loads, but ONE L2 request instead of four. (R9's 1.88x win.)
__device__ __forceinline__ uint4v load16_sc0(const unsigned* p) {
    uint4v r;
    asm volatile("global_load_dwordx4 %0, %1, off sc0"
                 : "=v"(r) : "v"(p) : "memory");
    return r;
}

// 16B coherent (L1-bypass) store: one L2 request instead of four.
__device__ __forceinline__ void store16_sc0(unsigned* p, uint4v v) {
    asm volatile("global_store_dwordx4 %0, %1, off sc0"
                 :: "v"(p), "v"(v) : "memory");
}

// Weight-stationary 2-layer LSTM, bf16-split-3 MFMA, ONE pass per superstep.
// 256 blocks = 16 row-slices (16 cols) x 16 batch-slices (16 batches).
// M=128 rows (L0 rows 0..63 = gate*16+col, L1 rows 64..127), N=16 batches.
// 8 waves = 8 16x16 tiles, FULL K per wave (L0: K=320 h0|x, L1: K=512 h0|h1).
//
// Sync (R10 = R9 skeleton): data stores -> vmcnt drain -> S3 -> one relaxed
// flag store per block to its OWN 64B line; consumers gather-poll + s_sleep.
// R10 deltas (same mechanism as R9's win — fewer L2 requests):
//   - h stores packed: 4 consecutive-ucc lanes -> 1 dwordx4 sc0 (3 shfl_down);
//     512 scalar stores/block -> 128 16B stores; shorter drain.
//   - poll loads restricted to lane<16 (others contribute true to __all):
//     4x less poll traffic contending with producers' flag/h stores.
__global__ __launch_bounds__(NTHR, 1)
void lstm2_mfma(const float* __restrict__ x,
                const float* __restrict__ Wih0, const float* __restrict__ Whh0,
                const float* __restrict__ bih0, const float* __restrict__ bhh0,
                const float* __restrict__ Wih1, const float* __restrict__ Whh1,
                const float* __restrict__ bih1, const float* __restrict__ bhh1,
                const float* __restrict__ Wf,   const float* __restrict__ bf,
                float* __restrict__ out, float* __restrict__ ws)
{
    cg::grid_group grid = cg::this_grid();
    const int tid = threadIdx.x;
    const int rs  = blockIdx.x >> 4;   // row-slice: cols [rs*16, rs*16+16)
    const int bs  = blockIdx.x & 15;   // batch-slice: batches [bs*16, bs*16+16)
    const int bbase = bs * 16;

    __shared__ short Bh[2][9472];      // 37.9 KB (h0|x: 16*PB0, h1: 16*PB1)
    __shared__ float zf[128][17];      // 8.7 KB

    unsigned* h0u = (unsigned*)ws;             // [2 parity][256 batch][256 col] packed
    unsigned* h1u = (unsigned*)ws + 2 * 256 * 256;
    unsigned* syn = (unsigned*)ws + 4 * 256 * 256;
    // flag(bs,rs) = syn[(bs*16+rs)*16] -> 256 flags, one 64B line each, 16KB

    // ---- init ----
    for (int i = blockIdx.x * NTHR + tid; i < 4 * 256 * 256; i += NBLK * NTHR)
        ((unsigned*)ws)[i] = 0u;
    if (tid == 0) STOREX(&syn[(bs * 16 + rs) * 16], 0u);
    if (rs == 0 && tid < 16) out[bbase + tid] = bf[0];

    // ---- mfma lane decode ----
    const int w = tid >> 6, lane = tid & 63;
    const int quad = lane >> 4, n16 = lane & 15;
    const int bBase0 = n16 * PB0 + quad * 8;
    const int bBase1 = B1B + n16 * PB1 + quad * 8;

    // ---- weight A-fragments -> registers (full K per wave) ----
    // Wave w<4: L0 tile rows w*16..+16 (within-layer row r = w*16+n16).
    // Wave w>=4: L1 tile rows (w-4)*16..+16.
    short8 wfh[16], wfl[16];
    {
        const int r = (w & 3) * 16 + n16;            // within-layer row 0..63
        const int g = r >> 4, cc = r & 15;
        const size_t grow = (size_t)(g * 256 + rs * 16 + cc);
        const int nkc = (w < 4) ? 10 : 16;
        #pragma unroll
        for (int kc = 0; kc < 16; ++kc) {
            if (kc < nkc) {
                const int k = kc * 32 + quad * 8;
                const float* src;
                if (w < 4)                           // L0: k<256 -> Whh0, else Wih0
                    src = (k < 256) ? &Whh0[grow * 256 + k] : &Wih0[grow * 64 + (k - 256)];
                else                                 // L1: k<256 -> Wih1 (vs h0), else Whh1 (vs h1)
                    src = (k < 256) ? &Wih1[grow * 256 + k] : &Whh1[grow * 256 + (k - 256)];
                float4 f0 = *(const float4*)src;
                float4 f1 = *(const float4*)(src + 4);
                short8 hi, lo; short2 t;
                t = split1(f0.x); hi[0] = t.x; lo[0] = t.y;
                t = split1(f0.y); hi[1] = t.x; lo[1] = t.y;
                t = split1(f0.z); hi[2] = t.x; lo[2] = t.y;
                t = split1(f0.w); hi[3] = t.x; lo[3] = t.y;
                t = split1(f1.x); hi[4] = t.x; lo[4] = t.y;
                t = split1(f1.y); hi[5] = t.x; lo[5] = t.y;
                t = split1(f1.z); hi[6] = t.x; lo[6] = t.y;
                t = split1(f1.w); hi[7] = t.x; lo[7] = t.y;
                wfh[kc] = hi; wfl[kc] = lo;
            }
        }
    }

    // ---- updater decode: all 512 threads, cell (layer ul, col ucc, batch ub) ----
    const int ul = tid >> 8, ub = (tid >> 4) & 15, ucc = tid & 15;
    const int ucol = rs * 16 + ucc;
    float ubias[4];
    {
        const float* bi = ul ? bih1 : bih0;
        const float* bh = ul ? bhh1 : bhh0;
        #pragma unroll
        for (int g = 0; g < 4; ++g) ubias[g] = bi[g * 256 + ucol] + bh[g * 256 + ucol];
    }
    float cst = 0.f, h1last = 0.f;

    // staging decode
    const int sn = tid >> 5, sk = (tid & 31) * 8;
    const int xn = tid >> 4, xd4 = (tid & 15) * 4;

    grid.sync();   // init visible device-wide

    float4 xpre;
    if (tid < 256)
        xpre = *(const float4*)&x[((size_t)(bbase + xn) * Tsz + 0) * 64 + xd4];

    for (int s = 0; s <= Tsz; ++s) {
        const int rp = (s + 1) & 1;   // parity of h0[s-1]
        const int rq = s & 1;         // parity of h1[s-2]

        // ---- wait for superstep s-1 of this bs-group: lanes 0..15 gather-poll
        //      16 distinct cachelines; lanes 16..63 contribute true to __all
        //      (4x less poll traffic against producers' stores) ----
        if (s > 0) {
            const unsigned* fl = &syn[(bs * 16 + (lane & 15)) * 16];
            int guard = 0;
            for (;;) {
                bool ok = true;
                if (lane < 16) ok = (LOADX(fl) >= (unsigned)s);
                if (__all((int)ok)) break;
                if (++guard > SPIN_GUARD) break;   // watchdog: fail, don't hang
                __builtin_amdgcn_s_sleep(1);
            }
            asm volatile("" ::: "memory");   // keep staging loads below the poll
        }

        // ---- stage h0[s-1], h1[s-2]: 16B sc0 loads + v_perm unpack, x[s] ----
        {
            const unsigned* q0 = &h0u[((size_t)(rp * 256) + bbase + sn) * 256 + sk];
            const unsigned* q1 = &h1u[((size_t)(rq * 256) + bbase + sn) * 256 + sk];
            uint4v A0 = load16_sc0(q0);
            uint4v A1 = load16_sc0(q0 + 4);
            uint4v B0 = load16_sc0(q1);
            uint4v B1 = load16_sc0(q1 + 4);
            asm volatile("s_waitcnt vmcnt(0)" ::: "memory");
            unsigned a[8], b[8];
            a[0] = A0.x; a[1] = A0.y; a[2] = A0.z; a[3] = A0.w;
            a[4] = A1.x; a[5] = A1.y; a[6] = A1.z; a[7] = A1.w;
            b[0] = B0.x; b[1] = B0.y; b[2] = B0.z; b[3] = B0.w;
            b[4] = B1.x; b[5] = B1.y; b[6] = B1.z; b[7] = B1.w;
            uint4 hi4, lo4;
            hi4.x = __builtin_amdgcn_perm(a[1], a[0], 0x07060302u);
            hi4.y = __builtin_amdgcn_perm(a[3], a[2], 0x07060302u);
            hi4.z = __builtin_amdgcn_perm(a[5], a[4], 0x07060302u);
            hi4.w = __builtin_amdgcn_perm(a[7], a[6], 0x07060302u);
            lo4.x = __builtin_amdgcn_perm(a[1], a[0], 0x05040100u);
            lo4.y = __builtin_amdgcn_perm(a[3], a[2], 0x05040100u);
            lo4.z = __builtin_amdgcn_perm(a[5], a[4], 0x05040100u);
            lo4.w = __builtin_amdgcn_perm(a[7], a[6], 0x05040100u);
            *(uint4*)&Bh[0][sn * PB0 + sk] = hi4;
            *(uint4*)&Bh[1][sn * PB0 + sk] = lo4;
            hi4.x = __builtin_amdgcn_perm(b[1], b[0], 0x07060302u);
            hi4.y = __builtin_amdgcn_perm(b[3], b[2], 0x07060302u);
            hi4.z = __builtin_amdgcn_perm(b[5], b[4], 0x07060302u);
            hi4.w = __builtin_amdgcn_perm(b[7], b[6], 0x07060302u);
            lo4.x = __builtin_amdgcn_perm(b[1], b[0], 0x05040100u);
            lo4.y = __builtin_amdgcn_perm(b[3], b[2], 0x05040100u);
            lo4.z = __builtin_amdgcn_perm(b[5], b[4], 0x05040100u);
            lo4.w = __builtin_amdgcn_perm(b[7], b[6], 0x05040100u);
            *(uint4*)&Bh[0][B1B + sn * PB1 + sk] = hi4;
            *(uint4*)&Bh[1][B1B + sn * PB1 + sk] = lo4;
        }
        if (s < Tsz && tid < 256) {
            float4 xv = xpre;
            short4v xh, xl; short2 t;
            t = split1(xv.x); xh[0] = t.x; xl[0] = t.y;
            t = split1(xv.y); xh[1] = t.x; xl[1] = t.y;
            t = split1(xv.z); xh[2] = t.x; xl[2] = t.y;
            t = split1(xv.w); xh[3] = t.x; xl[3] = t.y;
            *(short4v*)&Bh[0][xn * PB0 + 256 + xd4] = xh;
            *(short4v*)&Bh[1][xn * PB0 + 256 + xd4] = xl;
        }
        __syncthreads();   // S1: Bh staged

        // x prefetch for next superstep (drains naturally before use)
        if (tid < 256 && s + 1 < Tsz)
            xpre = *(const float4*)&x[((size_t)(bbase + xn) * Tsz + (s + 1)) * 64 + xd4];

        // ---- MFMA: full-K tile per wave, register A-frags, 3 independent
        //      accumulator chains (hi*hi / hi*lo / lo*hi) ----
        float4v a0 = {0.f, 0.f, 0.f, 0.f};
        float4v a1 = {0.f, 0.f, 0.f, 0.f};
        float4v a2 = {0.f, 0.f, 0.f, 0.f};
        if (w < 4) {                         // L0: K=320 over h0|x
            #pragma unroll
            for (int kc = 0; kc < 10; ++kc) {
                const int bo = bBase0 + kc * 32;
                short8 bh2 = *(const short8*)&Bh[0][bo];
                short8 bl2 = *(const short8*)&Bh[1][bo];
                a0 = MFMA16(wfh[kc], bh2, a0);
                a1 = MFMA16(wfh[kc], bl2, a1);
                a2 = MFMA16(wfl[kc], bh2, a2);
            }
        } else {                             // L1: K=512 (h0 then h1)
            #pragma unroll
            for (int kc = 0; kc < 8; ++kc) {
                const int bo = bBase0 + kc * 32;
                short8 bh2 = *(const short8*)&Bh[0][bo];
                short8 bl2 = *(const short8*)&Bh[1][bo];
                a0 = MFMA16(wfh[kc], bh2, a0);
                a1 = MFMA16(wfh[kc], bl2, a1);
                a2 = MFMA16(wfl[kc], bh2, a2);
            }
            #pragma unroll
            for (int kc = 8; kc < 16; ++kc) {
                const int bo = bBase1 + (kc - 8) * 32;
                short8 bh2 = *(const short8*)&Bh[0][bo];
                short8 bl2 = *(const short8*)&Bh[1][bo];
                a0 = MFMA16(wfh[kc], bh2, a0);
                a1 = MFMA16(wfh[kc], bl2, a1);
                a2 = MFMA16(wfl[kc], bh2, a2);
            }
        }
        float4v acc = (a0 + a1) + a2;
        #pragma unroll
        for (int r = 0; r < 4; ++r)
            zf[w * 16 + quad * 4 + r][n16] = acc[r];
        __syncthreads();   // S2: zf complete

        // ---- cell update + PACKED h store (4 lanes -> 1 dwordx4 sc0) ----
        {
            const bool active = ul ? (s >= 1) : (s < Tsz);   // wave-uniform
            unsigned pk = 0u;
            if (active) {
                const int mb = ul * 64 + ucc;
                float z0 = zf[mb +  0][ub] + ubias[0];
                float z1 = zf[mb + 16][ub] + ubias[1];
                float z2 = zf[mb + 32][ub] + ubias[2];
                float z3 = zf[mb + 48][ub] + ubias[3];
                float ii = sigm(z0), ff = sigm(z1);
                float gg = tanh_fast(z2), oo = sigm(z3);
                float c = ff * cst + ii * gg; cst = c;
                float hval = oo * tanh_fast(c);
                if (ul) h1last = hval;
                short2 hl = split1(hval);
                pk = ((unsigned)(unsigned short)hl.x << 16) |
                     (unsigned)(unsigned short)hl.y;
            }
            // lanes ucc, ucc+1, ucc+2, ucc+3 share quad/ub/ul -> combine
            unsigned p1 = __shfl_down(pk, 1);
            unsigned p2 = __shfl_down(pk, 2);
            unsigned p3 = __shfl_down(pk, 3);
            if (active && (ucc & 3) == 0) {
                uint4v v; v.x = pk; v.y = p1; v.z = p2; v.w = p3;
                unsigned* dst = ul
                    ? &h1u[((size_t)(((s + 1) & 1) * 256) + bbase + ub) * 256 + ucol]
                    : &h0u[((size_t)((s & 1) * 256) + bbase + ub) * 256 + ucol];
                store16_sc0(dst, v);
            }
        }

        // ---- drain h stores (explicit: inline-asm stores aren't compiler-
        //      tracked), S3, then one parallel store to our OWN flag line ----
        asm volatile("s_waitcnt vmcnt(0)" ::: "memory");
        __syncthreads();   // S3
        if (tid == 0)
            STOREX(&syn[(bs * 16 + rs) * 16], (unsigned)(s + 1));
    }

    // ---- epilogue: out[b] += sum_cols h1_final * Wf ----
    if (ul == 1) {
        atomicAdd(&out[bbase + ub], h1last * Wf[ucol]);
    }
}

extern "C" void kernel_launch(void* const* d_in, const int* in_sizes, int n_in,
                              void* d_out, int out_size, void* d_ws, size_t ws_size,
                              hipStream_t stream) {
    const float* x    = (const float*)d_in[0];
    const float* Wih0 = (const float*)d_in[1];
    const float* Whh0 = (const float*)d_in[2];
    const float* bih0 = (const float*)d_in[3];
    const float* bhh0 = (const float*)d_in[4];
    const float* Wih1 = (const float*)d_in[5];
    const float* Whh1 = (const float*)d_in[6];
    const float* bih1 = (const float*)d_in[7];
    const float* bhh1 = (const float*)d_in[8];
    const float* Wf   = (const float*)d_in[9];
    const float* bf   = (const float*)d_in[10];
    float* out = (float*)d_out;
    float* ws  = (float*)d_ws;   // 1 MB packed h buffers + 16 KB flag area

    void* args[] = {
        (void*)&x, (void*)&Wih0, (void*)&Whh0, (void*)&bih0, (void*)&bhh0,
        (void*)&Wih1, (void*)&Whh1, (void*)&bih1, (void*)&bhh1,
        (void*)&Wf, (void*)&bf, (void*)&out, (void*)&ws
    };
    hipLaunchCooperativeKernel((void*)lstm2_mfma, dim3(NBLK), dim3(NTHR),
                               args, 0, stream);
}